// Round 1
// baseline (191.766 us; speedup 1.0000x reference)
//
#include <hip/hip_runtime.h>
#include <math.h>

// Problem constants (fixed by reference)
#define BATCH        32768
#define IN_CH        512
#define OUT_CH       1024
#define NP           17     // NUM_POINTS
#define NSTEP        3

// Each thread: 1 float4 of data (4 input channels) -> 8 output floats.
// Total float4s = 32768*512/4 = 4,194,304 = 16384 blocks * 256 threads.
//
// Step-body instruction economy vs previous version (34 -> ~20 VALU/body):
//  - wrap-free 19-entry biased table: tab[j] = orig[(j+9)%17], indexed bgn+8.
//    The torch negative-wrap (shift/and/add x2 = 6 ops) folds into table
//    construction; the +8 bias folds into the ds_read offset immediate (free).
//  - angle table pre-scaled by 1/2pi -> v_sin/v_cos fed directly in
//    revolutions (drops the two 1/2pi muls inside __sinf/__cosf).
//  - coeff/bias pre-doubled: __expf(fmaf(d,2c,2b)) is bit-identical to
//    __expf(2*fmaf(d,c,b)) (x2 scaling exact in fp32).
//  - +-15 clamp dropped: bit-identical u for all reachable t (|t| <~ 16);
//    fminf(u, FLT_MAX) keeps the inf -> NaN guard at 1 op.
//  - delta-form lerp fma(pos, te-tb, tb) drops om = 1-pos.
// Preserved exactly (boundary semantics): same u, same (u-1)*rcp(u+1), same
// fmaf(th,8.5,1), independent end = floor(index+1) (NOT bgn+1 -- rare
// binade-boundary flips must land on the reference's side), dual gather.

__global__ __launch_bounds__(256) void mac_kernel(
    const float* __restrict__ data,
    const float* __restrict__ angles,
    const float* __restrict__ velocity,
    const float* __restrict__ attention,
    const float* __restrict__ coeffp,
    const float* __restrict__ biasp,
    float* __restrict__ out)
{
    // Biased, wrap-free interleaved {velocity, angle/2pi} table.
    // 19 float2 entries over 32 banks: entries j and j+16 alias -> at most
    // 2-way conflict (free, m136); duplicate lane indices broadcast.
    __shared__ float2 tab[NP + 2];
    const int tid = threadIdx.x;
    const int gid = blockIdx.x * 256 + tid;        // float4 index into data

    const float4 d4 = ((const float4*)data)[gid];  // issue global load early

    if (tid < NP + 2) {
        int src = tid + 9;                         // (tid + 9) % 17
        if (src >= NP) src -= NP;
        tab[tid] = make_float2(velocity[src],
                               angles[src] * 0.15915494309189535f);
    }
    const float coeff2 = 2.0f * coeffp[0];
    const float bias2  = 2.0f * biasp[0];
    __syncthreads();

    float x[4] = {d4.x, d4.y, d4.z, d4.w};
    const float INV3 = 0.33333333333333333f;       // 1/NUM_STEPS

    #pragma unroll
    for (int s = 0; s < NSTEP; ++s) {
        #pragma unroll
        for (int k = 0; k < 4; ++k) {
            const float dv = x[k];
            // u = e^{2t}, t = d*coeff + bias  (bit-identical to prior version)
            float u = __expf(fmaf(dv, coeff2, bias2));
            u = fminf(u, 3.402823466e38f);         // inf guard only; identity otherwise
            const float th    = (u - 1.0f) * __builtin_amdgcn_rcpf(u + 1.0f);
            const float index = fmaf(th, 8.5f, 1.0f);   // in (-7.5, 9.5)

            const float fb  = floorf(index);
            const int   bgn = (int)fb;
            // Replicate reference exactly: end = floor(index + 1.0), NOT bgn+1.
            const int   end = (int)floorf(index + 1.0f);
            const float pos = index - fb;

            const float2 tb = tab[bgn + 8];        // +8 bias -> ds offset:64
            const float2 te = tab[end + 8];
            const float velo = fmaf(pos, te.x - tb.x, tb.x);
            const float angr = fmaf(pos, te.y - tb.y, tb.y);  // in revolutions

            const float sn = __builtin_amdgcn_sinf(angr);     // v_sin_f32
            const float cs = __builtin_amdgcn_cosf(angr);     // v_cos_f32
            // step = velo*cos + d*velo*sin = velo * (cos + d*sin)
            x[k] = fmaf(velo * fmaf(dv, sn, cs), INV3, x[k]);
        }
    }

    // Output mapping: data element (b, c) -> out[b*1024 + 2c + {0,1}]
    const int b  = gid >> 7;          // gid / (512/4)
    const int c4 = gid & 127;
    const float4* attv = (const float4*)attention;
    const float4 a0 = attv[c4 * 2];
    const float4 a1 = attv[c4 * 2 + 1];

    float4 o0 = make_float4(a0.x * x[0], a0.y * x[0], a0.z * x[1], a0.w * x[1]);
    float4 o1 = make_float4(a1.x * x[2], a1.y * x[2], a1.z * x[3], a1.w * x[3]);

    float4* outv = (float4*)out;
    const int base = b * 256 + c4 * 2;            // float4 index into out
    outv[base]     = o0;
    outv[base + 1] = o1;
}

extern "C" void kernel_launch(void* const* d_in, const int* in_sizes, int n_in,
                              void* d_out, int out_size, void* d_ws, size_t ws_size,
                              hipStream_t stream) {
    const float* data      = (const float*)d_in[0];
    const float* angles    = (const float*)d_in[1];
    const float* velocity  = (const float*)d_in[2];
    const float* attention = (const float*)d_in[3];
    const float* coeff     = (const float*)d_in[4];
    const float* bias      = (const float*)d_in[5];
    float* out = (float*)d_out;

    const int total_f4 = BATCH * IN_CH / 4;       // 4,194,304
    const int block = 256;
    const int grid  = total_f4 / block;           // 16384
    mac_kernel<<<grid, block, 0, stream>>>(data, angles, velocity, attention,
                                           coeff, bias, out);
}